// Round 1
// baseline (458.963 us; speedup 1.0000x reference)
//
#include <hip/hip_runtime.h>

#define Bn 64
#define Cc 384
#define NHh 6
#define HD 64
#define Hh 32
#define Ww 32
#define LQ 1025
#define LKV 257
#define TPAD 288
#define EPSf 1e-5f
#define SCALEf 0.05103103630798288f   // 384^-0.5

typedef float f32x4 __attribute__((ext_vector_type(4)));
typedef unsigned short u16x8 __attribute__((ext_vector_type(8)));

__device__ __forceinline__ void mfma_16x16x32_bf16(f32x4& d, u16x8 a, u16x8 b) {
  // D = A*B + D ; A: 16x32, row = lane&15, k = (lane>>4)*8 + i (contig 8)
  //              B: 32x16, col = lane&15, k = (lane>>4)*8 + i
  //              D: col = lane&15, row = (lane>>4)*4 + reg
  asm("v_mfma_f32_16x16x32_bf16 %0, %1, %2, %0" : "+v"(d) : "v"(a), "v"(b));
}

__device__ __forceinline__ unsigned short f2bf(float f) {
  unsigned int u = __builtin_bit_cast(unsigned int, f);
  u += 0x7fffu + ((u >> 16) & 1u);
  return (unsigned short)(u >> 16);
}

// ---------------- zero fill (avoid hipMemsetAsync-in-capture risk) -------------
__global__ void zero_kernel(unsigned short* p, int n) {
  int i = blockIdx.x * 256 + threadIdx.x;
  if (i < n) p[i] = 0;
}

// ---------------- fp32 -> bf16 weight conversion ------------------------------
__global__ void cvt_w_kernel(const float* wq, const float* wk, const float* wv,
                             unsigned short* dst) {
  int i = blockIdx.x * 256 + threadIdx.x;            // 3*384*384
  int which = i / (Cc * Cc), r = i % (Cc * Cc);
  const float* s = (which == 0) ? wq : (which == 1) ? wk : wv;
  dst[i] = f2bf(s[r]);
}

// ---------------- cls token copy into activation row 0 ------------------------
__global__ void cls_kernel(const float* hidden, unsigned short* q_act,
                           unsigned short* k_act, unsigned short* v_act) {
  int i = blockIdx.x * 256 + threadIdx.x;            // Bn*Cc
  int b = i / Cc, c = i % Cc;
  unsigned short v = f2bf(hidden[(size_t)b * LQ * Cc + c]);
  q_act[(size_t)b * LQ * Cc + c] = v;
  k_act[(size_t)b * LKV * Cc + c] = v;
  v_act[(size_t)b * LKV * Cc + c] = v;
}

// ---------------- depthwise conv 3x3 s1 + BN for q ----------------------------
__global__ void conv_q_kernel(const float* hidden, const float* cw,
                              const float* gam, const float* bet,
                              const float* mu, const float* var,
                              unsigned short* q_act) {
  int e = blockIdx.x * 256 + threadIdx.x;
  int c = e % Cc; int r = e / Cc;
  int j = r % Ww; r /= Ww;
  int ig = r % 8; int b = r / 8;
  int i0 = ig * 4;

  float w[9];
#pragma unroll
  for (int t = 0; t < 9; ++t) w[t] = cw[c * 9 + t];
  float inv = gam[c] * rsqrtf(var[c] + EPSf);
  float add = bet[c] - mu[c] * inv;

  float acc[4] = {0.f, 0.f, 0.f, 0.f};
  const float* hb = hidden + (size_t)b * LQ * Cc + Cc + c;  // (h,w) -> +(h*32+w)*Cc
#pragma unroll
  for (int dh = 0; dh < 6; ++dh) {
    int h = i0 - 1 + dh;
    if (h < 0 || h >= Hh) continue;
    const float* hr = hb + (size_t)(h * Ww + j) * Cc;
    float xl = (j > 0)      ? hr[-Cc] : 0.f;
    float xc = hr[0];
    float xr = (j < Ww - 1) ? hr[Cc]  : 0.f;
#pragma unroll
    for (int dy = 0; dy < 3; ++dy) {
      int oi = dh - dy;                 // output row offset; compile-time
      if (oi >= 0 && oi < 4)
        acc[oi] += w[dy * 3 + 0] * xl + w[dy * 3 + 1] * xc + w[dy * 3 + 2] * xr;
    }
  }
#pragma unroll
  for (int oi = 0; oi < 4; ++oi) {
    int pos = (i0 + oi) * Ww + j;
    q_act[((size_t)b * LQ + 1 + pos) * Cc + c] = f2bf(acc[oi] * inv + add);
  }
}

// ---------------- depthwise conv 3x3 s2 + BN for k and v (fused) --------------
__global__ void conv_kv_kernel(const float* hidden,
                               const float* cwk, const float* gk, const float* bk,
                               const float* mk, const float* vk,
                               const float* cwv, const float* gv, const float* bv,
                               const float* mv, const float* vv,
                               unsigned short* k_act, unsigned short* v_act) {
  int e = blockIdx.x * 256 + threadIdx.x;
  int c = e % Cc; int r = e / Cc;
  int j = r % 16; r /= 16;
  int i = r % 16; int b = r / 16;

  float acck = 0.f, accv = 0.f;
  const float* hb = hidden + (size_t)b * LQ * Cc + Cc + c;
#pragma unroll
  for (int dy = 0; dy < 3; ++dy) {
    int h = 2 * i + dy - 1;
    if (h < 0 || h >= Hh) continue;
#pragma unroll
    for (int dx = 0; dx < 3; ++dx) {
      int w = 2 * j + dx - 1;
      if (w < 0 || w >= Ww) continue;
      float x = hb[(size_t)(h * Ww + w) * Cc];
      acck += cwk[c * 9 + dy * 3 + dx] * x;
      accv += cwv[c * 9 + dy * 3 + dx] * x;
    }
  }
  float invk = gk[c] * rsqrtf(vk[c] + EPSf); float addk = bk[c] - mk[c] * invk;
  float invv = gv[c] * rsqrtf(vv[c] + EPSf); float addv = bv[c] - mv[c] * invv;
  int pos = i * 16 + j;
  k_act[((size_t)b * LKV + 1 + pos) * Cc + c] = f2bf(acck * invk + addk);
  v_act[((size_t)b * LKV + 1 + pos) * Cc + c] = f2bf(accv * invv + addv);
}

// ---------------- projection GEMM: out[m,o] = sum_c A[m,c]*W[o,c] + bias[o] ----
// mode 0 (q): out[m*384 + o]                     (m = b*1025 + l)
// mode 1 (k): b=m/257, t=m%257 -> out[(b*288+t)*384 + o]
// mode 2 (v): b=m/257, t=m%257 -> out[(b*384+o)*288 + t]   (transposed for PV)
__global__ __launch_bounds__(256) void proj_gemm_kernel(
    const unsigned short* A, const unsigned short* Wb, const float* bias,
    unsigned short* out, int mode) {
  __shared__ __align__(16) unsigned short a_lds[64][40];
  __shared__ __align__(16) unsigned short b_lds[128][40];
  int m0 = blockIdx.x * 64;
  int n0 = blockIdx.y * 128;
  int tid = threadIdx.x;
  int lane = tid & 63, wid = tid >> 6;
  int wm = wid >> 1, wn = wid & 1;
  int lr = lane & 15, lg = lane >> 4;

  const f32x4 fz = {0.f, 0.f, 0.f, 0.f};
  f32x4 acc[2][4];
#pragma unroll
  for (int i = 0; i < 2; ++i)
#pragma unroll
    for (int j = 0; j < 4; ++j) acc[i][j] = fz;

  int srow = tid >> 2, scg = tid & 3;
  for (int kk = 0; kk < Cc; kk += 32) {
    *(u16x8*)&a_lds[srow][scg * 8] =
        *(const u16x8*)&A[(size_t)(m0 + srow) * Cc + kk + scg * 8];
#pragma unroll
    for (int p = 0; p < 2; ++p) {
      int brow = srow + p * 64;
      *(u16x8*)&b_lds[brow][scg * 8] =
          *(const u16x8*)&Wb[(size_t)(n0 + brow) * Cc + kk + scg * 8];
    }
    __syncthreads();
    u16x8 af[2], bfr[4];
#pragma unroll
    for (int mi = 0; mi < 2; ++mi)
      af[mi] = *(const u16x8*)&a_lds[wm * 32 + mi * 16 + lr][lg * 8];
#pragma unroll
    for (int ni = 0; ni < 4; ++ni)
      bfr[ni] = *(const u16x8*)&b_lds[wn * 64 + ni * 16 + lr][lg * 8];
#pragma unroll
    for (int mi = 0; mi < 2; ++mi)
#pragma unroll
      for (int ni = 0; ni < 4; ++ni)
        mfma_16x16x32_bf16(acc[mi][ni], af[mi], bfr[ni]);
    __syncthreads();
  }

#pragma unroll
  for (int ni = 0; ni < 4; ++ni) {
    int col = n0 + wn * 64 + ni * 16 + lr;
    float bv = bias[col];
#pragma unroll
    for (int mi = 0; mi < 2; ++mi) {
      int rowbase = m0 + wm * 32 + mi * 16 + lg * 4;
#pragma unroll
      for (int rg = 0; rg < 4; ++rg) {
        int row = rowbase + rg;
        unsigned short bv16 = f2bf(acc[mi][ni][rg] + bv);
        if (mode == 0) {
          out[(size_t)row * Cc + col] = bv16;
        } else {
          int bb = row / LKV, t = row % LKV;
          if (mode == 1) out[((size_t)bb * TPAD + t) * Cc + col] = bv16;
          else           out[((size_t)bb * Cc + col) * TPAD + t] = bv16;
        }
      }
    }
  }
}

// ---------------- fused attention: per-wave 16 q-rows, full softmax ------------
__global__ __launch_bounds__(256) void attn_kernel(
    const unsigned short* q_proj, const unsigned short* k_proj,
    const unsigned short* v_t, float* out) {
  __shared__ __align__(16) unsigned short P[4][16][296];  // per-wave, pad->conflict-free
  int wid = threadIdx.x >> 6, lane = threadIdx.x & 63;
  int lr = lane & 15, lg = lane >> 4;
  int h = blockIdx.y, b = blockIdx.z;
  int qtile = blockIdx.x * 4 + wid;
  if (qtile >= 65) return;                 // wave-uniform; no barriers in kernel
  int qbase = qtile * 16;

  int qrow = qbase + lr; if (qrow > LQ - 1) qrow = LQ - 1;   // clamp tail
  const u16x8* qp =
      (const u16x8*)&q_proj[((size_t)b * LQ + qrow) * Cc + h * HD + lg * 8];
  u16x8 qa0 = qp[0], qa1 = qp[4];

  float s[18][4];
  float mr[4] = {-1e30f, -1e30f, -1e30f, -1e30f};
#pragma unroll
  for (int t = 0; t < 18; ++t) {
    const u16x8* kp =
        (const u16x8*)&k_proj[((size_t)b * TPAD + t * 16 + lr) * Cc + h * HD + lg * 8];
    u16x8 kb0 = kp[0], kb1 = kp[4];
    f32x4 acc = {0.f, 0.f, 0.f, 0.f};
    mfma_16x16x32_bf16(acc, qa0, kb0);
    mfma_16x16x32_bf16(acc, qa1, kb1);
    bool valid = (t * 16 + lr) < LKV;      // acc col = lane&15
#pragma unroll
    for (int rg = 0; rg < 4; ++rg) {
      float v = valid ? acc[rg] * SCALEf : -1e30f;
      s[t][rg] = v;
      mr[rg] = fmaxf(mr[rg], v);
    }
  }
#pragma unroll
  for (int off = 1; off < 16; off <<= 1)
#pragma unroll
    for (int rg = 0; rg < 4; ++rg)
      mr[rg] = fmaxf(mr[rg], __shfl_xor(mr[rg], off, 64));

  float sum[4] = {0.f, 0.f, 0.f, 0.f};
#pragma unroll
  for (int t = 0; t < 18; ++t) {
#pragma unroll
    for (int rg = 0; rg < 4; ++rg) {
      float p = (s[t][rg] <= -1e29f) ? 0.f : __expf(s[t][rg] - mr[rg]);
      sum[rg] += p;
      P[wid][lg * 4 + rg][t * 16 + lr] = f2bf(p);
    }
  }
#pragma unroll
  for (int off = 1; off < 16; off <<= 1)
#pragma unroll
    for (int rg = 0; rg < 4; ++rg)
      sum[rg] += __shfl_xor(sum[rg], off, 64);

  const f32x4 fz = {0.f, 0.f, 0.f, 0.f};
  f32x4 o[4];
#pragma unroll
  for (int dt = 0; dt < 4; ++dt) o[dt] = fz;
#pragma unroll
  for (int kk = 0; kk < 9; ++kk) {
    u16x8 pa = *(const u16x8*)&P[wid][lr][kk * 32 + lg * 8];
#pragma unroll
    for (int dt = 0; dt < 4; ++dt) {
      const u16x8* vp = (const u16x8*)
          &v_t[((size_t)b * Cc + h * HD + dt * 16 + lr) * TPAD + kk * 32 + lg * 8];
      mfma_16x16x32_bf16(o[dt], pa, vp[0]);
    }
  }
#pragma unroll
  for (int rg = 0; rg < 4; ++rg) {
    int row = qbase + lg * 4 + rg;
    if (row > LQ - 1) continue;
    float rs = 1.f / sum[rg];
#pragma unroll
    for (int dt = 0; dt < 4; ++dt)
      out[((size_t)b * LQ + row) * Cc + h * HD + dt * 16 + lr] = o[dt][rg] * rs;
  }
}

extern "C" void kernel_launch(void* const* d_in, const int* in_sizes, int n_in,
                              void* d_out, int out_size, void* d_ws, size_t ws_size,
                              hipStream_t stream) {
  const float* hidden   = (const float*)d_in[0];
  const float* conv_q_w = (const float*)d_in[1];
  const float* bn_q_g   = (const float*)d_in[2];
  const float* bn_q_b   = (const float*)d_in[3];
  const float* bn_q_m   = (const float*)d_in[4];
  const float* bn_q_v   = (const float*)d_in[5];
  const float* w_q      = (const float*)d_in[6];
  const float* b_q      = (const float*)d_in[7];
  const float* conv_k_w = (const float*)d_in[8];
  const float* bn_k_g   = (const float*)d_in[9];
  const float* bn_k_b   = (const float*)d_in[10];
  const float* bn_k_m   = (const float*)d_in[11];
  const float* bn_k_v   = (const float*)d_in[12];
  const float* w_k      = (const float*)d_in[13];
  const float* b_k      = (const float*)d_in[14];
  const float* conv_v_w = (const float*)d_in[15];
  const float* bn_v_g   = (const float*)d_in[16];
  const float* bn_v_b   = (const float*)d_in[17];
  const float* bn_v_m   = (const float*)d_in[18];
  const float* bn_v_v   = (const float*)d_in[19];
  const float* w_v      = (const float*)d_in[20];
  const float* b_v      = (const float*)d_in[21];
  float* out = (float*)d_out;

  char* ws = (char*)d_ws;
  unsigned short* q_act  = (unsigned short*)(ws + 0);          // 65600*384
  unsigned short* k_act  = (unsigned short*)(ws + 50380800);   // 16448*384
  unsigned short* v_act  = (unsigned short*)(ws + 63012864);   // 16448*384
  unsigned short* q_proj = (unsigned short*)(ws + 75644928);   // 65600*384
  unsigned short* k_proj = (unsigned short*)(ws + 126025728);  // 64*288*384
  unsigned short* v_t    = (unsigned short*)(ws + 140181504);  // 64*384*288
  unsigned short* wbf    = (unsigned short*)(ws + 154337280);  // 3*384*384

  // zero v_t so the t>=257 pad contributes exactly 0 in PV (and is NaN-free)
  zero_kernel<<<(Bn * Cc * TPAD + 255) / 256, 256, 0, stream>>>(v_t, Bn * Cc * TPAD);
  cvt_w_kernel<<<(3 * Cc * Cc) / 256, 256, 0, stream>>>(w_q, w_k, w_v, wbf);
  cls_kernel<<<(Bn * Cc) / 256, 256, 0, stream>>>(hidden, q_act, k_act, v_act);
  conv_q_kernel<<<(Bn * 8 * Ww * Cc) / 256, 256, 0, stream>>>(
      hidden, conv_q_w, bn_q_g, bn_q_b, bn_q_m, bn_q_v, q_act);
  conv_kv_kernel<<<(Bn * 16 * 16 * Cc) / 256, 256, 0, stream>>>(
      hidden, conv_k_w, bn_k_g, bn_k_b, bn_k_m, bn_k_v,
      conv_v_w, bn_v_g, bn_v_b, bn_v_m, bn_v_v, k_act, v_act);

  dim3 gq(1025, 3);
  proj_gemm_kernel<<<gq, 256, 0, stream>>>(q_act, wbf, b_q, q_proj, 0);
  dim3 gkv(257, 3);
  proj_gemm_kernel<<<gkv, 256, 0, stream>>>(k_act, wbf + Cc * Cc, b_k, k_proj, 1);
  proj_gemm_kernel<<<gkv, 256, 0, stream>>>(v_act, wbf + 2 * Cc * Cc, b_v, v_t, 2);

  dim3 ga(17, NHh, Bn);
  attn_kernel<<<ga, 256, 0, stream>>>(q_proj, k_proj, v_t, out);
}

// Round 2
// 352.835 us; speedup vs baseline: 1.3008x; 1.3008x over previous
//
#include <hip/hip_runtime.h>

#define Bn 64
#define Cc 384
#define NHh 6
#define HD 64
#define Hh 32
#define Ww 32
#define LQ 1025
#define LKV 257
#define TPAD 288
#define EPSf 1e-5f
#define SCALEf 0.05103103630798288f   // 384^-0.5

typedef float f32x4 __attribute__((ext_vector_type(4)));
typedef unsigned short u16x8 __attribute__((ext_vector_type(8)));
typedef unsigned short u16x4 __attribute__((ext_vector_type(4)));

__device__ __forceinline__ void mfma_16x16x32_bf16(f32x4& d, u16x8 a, u16x8 b) {
  // D = A*B + D ; A: 16x32, row = lane&15, k = (lane>>4)*8 + i (contig 8)
  //              B: 32x16, col = lane&15, k = (lane>>4)*8 + i
  //              D: col = lane&15, row = (lane>>4)*4 + reg
  asm("v_mfma_f32_16x16x32_bf16 %0, %1, %2, %0" : "+v"(d) : "v"(a), "v"(b));
}

__device__ __forceinline__ unsigned short f2bf(float f) {
  unsigned int u = __builtin_bit_cast(unsigned int, f);
  u += 0x7fffu + ((u >> 16) & 1u);
  return (unsigned short)(u >> 16);
}

// ---------------- zero fill for v_t pad (NaN-safety in PV) --------------------
__global__ void zero_kernel(unsigned short* p, int n) {
  int i = blockIdx.x * 256 + threadIdx.x;
  if (i < n) p[i] = 0;
}

// ---------------- fp32 -> bf16 weight conversion ------------------------------
__global__ void cvt_w_kernel(const float* wq, const float* wk, const float* wv,
                             unsigned short* dst) {
  int i = blockIdx.x * 256 + threadIdx.x;            // 3*384*384
  int which = i / (Cc * Cc), r = i % (Cc * Cc);
  const float* s = (which == 0) ? wq : (which == 1) ? wk : wv;
  dst[i] = f2bf(s[r]);
}

// ---------------- cls token copy into activation row 0 ------------------------
__global__ void cls_kernel(const float* hidden, unsigned short* q_act,
                           unsigned short* k_act, unsigned short* v_act) {
  int i = blockIdx.x * 256 + threadIdx.x;            // Bn*Cc
  int b = i / Cc, c = i % Cc;
  unsigned short v = f2bf(hidden[(size_t)b * LQ * Cc + c]);
  q_act[(size_t)b * LQ * Cc + c] = v;
  k_act[(size_t)b * LKV * Cc + c] = v;
  v_act[(size_t)b * LKV * Cc + c] = v;
}

// ---------------- depthwise conv 3x3 s1 + BN for q ----------------------------
__global__ void conv_q_kernel(const float* hidden, const float* cw,
                              const float* gam, const float* bet,
                              const float* mu, const float* var,
                              unsigned short* q_act) {
  int e = blockIdx.x * 256 + threadIdx.x;
  int c = e % Cc; int r = e / Cc;
  int j = r % Ww; r /= Ww;
  int ig = r % 8; int b = r / 8;
  int i0 = ig * 4;

  float w[9];
#pragma unroll
  for (int t = 0; t < 9; ++t) w[t] = cw[c * 9 + t];
  float inv = gam[c] * rsqrtf(var[c] + EPSf);
  float add = bet[c] - mu[c] * inv;

  float acc[4] = {0.f, 0.f, 0.f, 0.f};
  const float* hb = hidden + (size_t)b * LQ * Cc + Cc + c;  // (h,w) -> +(h*32+w)*Cc
#pragma unroll
  for (int dh = 0; dh < 6; ++dh) {
    int h = i0 - 1 + dh;
    if (h < 0 || h >= Hh) continue;
    const float* hr = hb + (size_t)(h * Ww + j) * Cc;
    float xl = (j > 0)      ? hr[-Cc] : 0.f;
    float xc = hr[0];
    float xr = (j < Ww - 1) ? hr[Cc]  : 0.f;
#pragma unroll
    for (int dy = 0; dy < 3; ++dy) {
      int oi = dh - dy;                 // output row offset; compile-time
      if (oi >= 0 && oi < 4)
        acc[oi] += w[dy * 3 + 0] * xl + w[dy * 3 + 1] * xc + w[dy * 3 + 2] * xr;
    }
  }
#pragma unroll
  for (int oi = 0; oi < 4; ++oi) {
    int pos = (i0 + oi) * Ww + j;
    q_act[((size_t)b * LQ + 1 + pos) * Cc + c] = f2bf(acc[oi] * inv + add);
  }
}

// ---------------- depthwise conv 3x3 s2 + BN for k and v (fused) --------------
__global__ void conv_kv_kernel(const float* hidden,
                               const float* cwk, const float* gk, const float* bk,
                               const float* mk, const float* vk,
                               const float* cwv, const float* gv, const float* bv,
                               const float* mv, const float* vv,
                               unsigned short* k_act, unsigned short* v_act) {
  int e = blockIdx.x * 256 + threadIdx.x;
  int c = e % Cc; int r = e / Cc;
  int j = r % 16; r /= 16;
  int i = r % 16; int b = r / 16;

  float acck = 0.f, accv = 0.f;
  const float* hb = hidden + (size_t)b * LQ * Cc + Cc + c;
#pragma unroll
  for (int dy = 0; dy < 3; ++dy) {
    int h = 2 * i + dy - 1;
    if (h < 0 || h >= Hh) continue;
#pragma unroll
    for (int dx = 0; dx < 3; ++dx) {
      int w = 2 * j + dx - 1;
      if (w < 0 || w >= Ww) continue;
      float x = hb[(size_t)(h * Ww + w) * Cc];
      acck += cwk[c * 9 + dy * 3 + dx] * x;
      accv += cwv[c * 9 + dy * 3 + dx] * x;
    }
  }
  float invk = gk[c] * rsqrtf(vk[c] + EPSf); float addk = bk[c] - mk[c] * invk;
  float invv = gv[c] * rsqrtf(vv[c] + EPSf); float addv = bv[c] - mv[c] * invv;
  int pos = i * 16 + j;
  k_act[((size_t)b * LKV + 1 + pos) * Cc + c] = f2bf(acck * invk + addk);
  v_act[((size_t)b * LKV + 1 + pos) * Cc + c] = f2bf(accv * invv + addv);
}

// ---------------- projection GEMM: out[m,o] = sum_c A[m,c]*W[o,c] + bias[o] ----
// mode 0 (q): out[m*384 + o]                     (m = b*1025 + l)
// mode 1 (k): b=m/257, t=m%257 -> out[(b*288+t)*384 + o]
// mode 2 (v): b=m/257, t=m%257 -> out[(b*384+o)*288 + t]   (transposed for PV)
__global__ __launch_bounds__(256) void proj_gemm_kernel(
    const unsigned short* A, const unsigned short* Wb, const float* bias,
    unsigned short* out, int mode) {
  __shared__ __align__(16) unsigned short a_lds[64][40];
  __shared__ __align__(16) unsigned short b_lds[128][40];
  int m0 = blockIdx.x * 64;
  int n0 = blockIdx.y * 128;
  int tid = threadIdx.x;
  int lane = tid & 63, wid = tid >> 6;
  int wm = wid >> 1, wn = wid & 1;
  int lr = lane & 15, lg = lane >> 4;

  const f32x4 fz = {0.f, 0.f, 0.f, 0.f};
  f32x4 acc[2][4];
#pragma unroll
  for (int i = 0; i < 2; ++i)
#pragma unroll
    for (int j = 0; j < 4; ++j) acc[i][j] = fz;

  int srow = tid >> 2, scg = tid & 3;
  for (int kk = 0; kk < Cc; kk += 32) {
    *(u16x8*)&a_lds[srow][scg * 8] =
        *(const u16x8*)&A[(size_t)(m0 + srow) * Cc + kk + scg * 8];
#pragma unroll
    for (int p = 0; p < 2; ++p) {
      int brow = srow + p * 64;
      *(u16x8*)&b_lds[brow][scg * 8] =
          *(const u16x8*)&Wb[(size_t)(n0 + brow) * Cc + kk + scg * 8];
    }
    __syncthreads();
    u16x8 af[2], bfr[4];
#pragma unroll
    for (int mi = 0; mi < 2; ++mi)
      af[mi] = *(const u16x8*)&a_lds[wm * 32 + mi * 16 + lr][lg * 8];
#pragma unroll
    for (int ni = 0; ni < 4; ++ni)
      bfr[ni] = *(const u16x8*)&b_lds[wn * 64 + ni * 16 + lr][lg * 8];
#pragma unroll
    for (int mi = 0; mi < 2; ++mi)
#pragma unroll
      for (int ni = 0; ni < 4; ++ni)
        mfma_16x16x32_bf16(acc[mi][ni], af[mi], bfr[ni]);
    __syncthreads();
  }

#pragma unroll
  for (int ni = 0; ni < 4; ++ni) {
    int col = n0 + wn * 64 + ni * 16 + lr;
    float bv = bias[col];
#pragma unroll
    for (int mi = 0; mi < 2; ++mi) {
      int rowbase = m0 + wm * 32 + mi * 16 + lg * 4;
#pragma unroll
      for (int rg = 0; rg < 4; ++rg) {
        int row = rowbase + rg;
        unsigned short bv16 = f2bf(acc[mi][ni][rg] + bv);
        if (mode == 0) {
          out[(size_t)row * Cc + col] = bv16;
        } else {
          int bb = row / LKV, t = row % LKV;
          if (mode == 1) out[((size_t)bb * TPAD + t) * Cc + col] = bv16;
          else           out[((size_t)bb * Cc + col) * TPAD + t] = bv16;
        }
      }
    }
  }
}

// ---------------- fused attention: LDS-staged K/V, swapped QK^T ----------------
// grid (4, NH, B); block = 4 waves. Each block: one (b,h), ~16 q-tiles.
// K_s: [288][64] bf16, XOR-swizzled (byte ^= (row&7)<<4)  -> conflict-balanced
// V_s: [64][296] bf16 (d-major, t padded to 296)          -> conflict-balanced
// P_s: per-wave [16][40] bf16 chunk buffer for P relayout
__global__ __launch_bounds__(256) void attn_kernel(
    const unsigned short* q_proj, const unsigned short* k_proj,
    const unsigned short* v_t, float* out) {
  __shared__ __align__(16) unsigned short K_s[288 * 64];
  __shared__ __align__(16) unsigned short V_s[64][296];
  __shared__ __align__(16) unsigned short P_s[4][16][40];
  int tid = threadIdx.x;
  int wid = tid >> 6, lane = tid & 63;
  int lr = lane & 15, lg = lane >> 4;
  int h = blockIdx.y, b = blockIdx.z, bx = blockIdx.x;

  // ---- cooperative staging: K (2304 chunks) + V (2304 chunks), 16B each ----
  const unsigned short* kg = k_proj + (size_t)b * TPAD * Cc + h * HD;
  const unsigned short* vg = v_t + ((size_t)b * Cc + h * HD) * TPAD;
#pragma unroll
  for (int i = 0; i < 9; ++i) {
    int c = tid + i * 256;
    int row = c >> 3, c16 = c & 7;                    // 8 chunks per 64-col K row
    u16x8 kv = *(const u16x8*)&kg[(size_t)row * Cc + c16 * 8];
    *(u16x8*)((char*)K_s + row * 128 + ((c16 * 16) ^ ((row & 7) << 4))) = kv;
    int rv = c / 36, cv = c - rv * 36;                // 36 chunks per 288-col V row
    u16x8 vv = *(const u16x8*)&vg[(size_t)rv * TPAD + cv * 8];
    *(u16x8*)((char*)&V_s[rv][0] + cv * 16) = vv;
  }
  __syncthreads();

  int start = (bx == 0) ? 0 : 1 + bx * 16;            // 65 = 17+16+16+16
  int end = 17 + bx * 16;
  const f32x4 fz = {0.f, 0.f, 0.f, 0.f};

  for (int qt = start + wid; qt < end; qt += 4) {
    int qbase = qt * 16;
    int qrow = qbase + lr; if (qrow > LQ - 1) qrow = LQ - 1;   // clamp tail
    const u16x8* qp =
        (const u16x8*)&q_proj[((size_t)b * LQ + qrow) * Cc + h * HD + lg * 8];
    u16x8 q0 = qp[0], q1 = qp[4];

    // ---- QK^T swapped: A = K-tile (row=t), B = Q (col=q) ----
    // lane (lr,lg) holds s[q=lr][t = 16T + lg*4 + rg]
    int kb0 = lr * 128 + ((lg * 16) ^ ((lr & 7) << 4));
    int kb1 = kb0 ^ 64;
    f32x4 s[18];
#pragma unroll
    for (int T = 0; T < 18; ++T) {
      u16x8 ka = *(const u16x8*)((const char*)K_s + kb0 + T * 2048);
      u16x8 kc = *(const u16x8*)((const char*)K_s + kb1 + T * 2048);
      s[T] = fz;
      mfma_16x16x32_bf16(s[T], ka, q0);
      mfma_16x16x32_bf16(s[T], kc, q1);
    }

    // ---- softmax over t for this lane's q-row ----
    float m = -1e30f;
#pragma unroll
    for (int T = 0; T < 18; ++T)
#pragma unroll
      for (int rg = 0; rg < 4; ++rg) {
        int t = T * 16 + lg * 4 + rg;
        float v = (t < LKV) ? s[T][rg] * SCALEf : -1e30f;
        s[T][rg] = v;
        m = fmaxf(m, v);
      }
    m = fmaxf(m, __shfl_xor(m, 16, 64));
    m = fmaxf(m, __shfl_xor(m, 32, 64));
    float sum = 0.f;
#pragma unroll
    for (int T = 0; T < 18; ++T)
#pragma unroll
      for (int rg = 0; rg < 4; ++rg) {
        float p = __expf(s[T][rg] - m);               // masked -> exp(-huge) = 0
        s[T][rg] = p;
        sum += p;
      }
    sum += __shfl_xor(sum, 16, 64);
    sum += __shfl_xor(sum, 32, 64);

    // ---- PV, chunked through per-wave P_s: t in [kk*32, kk*32+32) ----
    f32x4 o[4];
#pragma unroll
    for (int dt = 0; dt < 4; ++dt) o[dt] = fz;
#pragma unroll
    for (int kk = 0; kk < 9; ++kk) {
      u16x4 w0, w1;
#pragma unroll
      for (int rg = 0; rg < 4; ++rg) {
        w0[rg] = f2bf(s[2 * kk][rg]);
        w1[rg] = f2bf(s[2 * kk + 1][rg]);
      }
      *(u16x4*)&P_s[wid][lr][lg * 4] = w0;            // t_local = lg*4+rg
      *(u16x4*)&P_s[wid][lr][16 + lg * 4] = w1;       // t_local = 16+lg*4+rg
      asm volatile("s_waitcnt lgkmcnt(0)" ::: "memory");
      u16x8 pa = *(const u16x8*)&P_s[wid][lr][lg * 8];  // A: row=q=lr, k=t_local
#pragma unroll
      for (int dt = 0; dt < 4; ++dt) {
        u16x8 vb = *(const u16x8*)&V_s[dt * 16 + lr][kk * 32 + lg * 8];
        mfma_16x16x32_bf16(o[dt], pa, vb);
      }
    }

    // ---- epilogue: o D-layout col=d=lr, row=q=lg*4+rg; fetch 1/sum per row ----
    float rs = 1.0f / sum;
#pragma unroll
    for (int rg = 0; rg < 4; ++rg) {
      int row = qbase + lg * 4 + rg;
      float rsv = __shfl(rs, lg * 4 + rg, 64);
      if (row <= LQ - 1) {
#pragma unroll
        for (int dt = 0; dt < 4; ++dt)
          out[((size_t)b * LQ + row) * Cc + h * HD + dt * 16 + lr] = o[dt][rg] * rsv;
      }
    }
  }
}

extern "C" void kernel_launch(void* const* d_in, const int* in_sizes, int n_in,
                              void* d_out, int out_size, void* d_ws, size_t ws_size,
                              hipStream_t stream) {
  const float* hidden   = (const float*)d_in[0];
  const float* conv_q_w = (const float*)d_in[1];
  const float* bn_q_g   = (const float*)d_in[2];
  const float* bn_q_b   = (const float*)d_in[3];
  const float* bn_q_m   = (const float*)d_in[4];
  const float* bn_q_v   = (const float*)d_in[5];
  const float* w_q      = (const float*)d_in[6];
  const float* b_q      = (const float*)d_in[7];
  const float* conv_k_w = (const float*)d_in[8];
  const float* bn_k_g   = (const float*)d_in[9];
  const float* bn_k_b   = (const float*)d_in[10];
  const float* bn_k_m   = (const float*)d_in[11];
  const float* bn_k_v   = (const float*)d_in[12];
  const float* w_k      = (const float*)d_in[13];
  const float* b_k      = (const float*)d_in[14];
  const float* conv_v_w = (const float*)d_in[15];
  const float* bn_v_g   = (const float*)d_in[16];
  const float* bn_v_b   = (const float*)d_in[17];
  const float* bn_v_m   = (const float*)d_in[18];
  const float* bn_v_v   = (const float*)d_in[19];
  const float* w_v      = (const float*)d_in[20];
  const float* b_v      = (const float*)d_in[21];
  float* out = (float*)d_out;

  char* ws = (char*)d_ws;
  unsigned short* q_act  = (unsigned short*)(ws + 0);          // 65600*384
  unsigned short* k_act  = (unsigned short*)(ws + 50380800);   // 16448*384
  unsigned short* v_act  = (unsigned short*)(ws + 63012864);   // 16448*384
  unsigned short* q_proj = (unsigned short*)(ws + 75644928);   // 65600*384
  unsigned short* k_proj = (unsigned short*)(ws + 126025728);  // 64*288*384
  unsigned short* v_t    = (unsigned short*)(ws + 140181504);  // 64*384*288
  unsigned short* wbf    = (unsigned short*)(ws + 154337280);  // 3*384*384

  // zero v_t so the t>=257 pad contributes exactly 0 in PV (and is NaN-free)
  zero_kernel<<<(Bn * Cc * TPAD + 255) / 256, 256, 0, stream>>>(v_t, Bn * Cc * TPAD);
  cvt_w_kernel<<<(3 * Cc * Cc) / 256, 256, 0, stream>>>(w_q, w_k, w_v, wbf);
  cls_kernel<<<(Bn * Cc) / 256, 256, 0, stream>>>(hidden, q_act, k_act, v_act);
  conv_q_kernel<<<(Bn * 8 * Ww * Cc) / 256, 256, 0, stream>>>(
      hidden, conv_q_w, bn_q_g, bn_q_b, bn_q_m, bn_q_v, q_act);
  conv_kv_kernel<<<(Bn * 16 * 16 * Cc) / 256, 256, 0, stream>>>(
      hidden, conv_k_w, bn_k_g, bn_k_b, bn_k_m, bn_k_v,
      conv_v_w, bn_v_g, bn_v_b, bn_v_m, bn_v_v, k_act, v_act);

  dim3 gq(1025, 3);
  proj_gemm_kernel<<<gq, 256, 0, stream>>>(q_act, wbf, b_q, q_proj, 0);
  dim3 gkv(257, 3);
  proj_gemm_kernel<<<gkv, 256, 0, stream>>>(k_act, wbf + Cc * Cc, b_k, k_proj, 1);
  proj_gemm_kernel<<<gkv, 256, 0, stream>>>(v_act, wbf + 2 * Cc * Cc, b_v, v_t, 2);

  dim3 ga(4, NHh, Bn);
  attn_kernel<<<ga, 256, 0, stream>>>(q_proj, k_proj, v_t, out);
}

// Round 3
// 257.422 us; speedup vs baseline: 1.7829x; 1.3706x over previous
//
#include <hip/hip_runtime.h>

#define Bn 64
#define Cc 384
#define NHh 6
#define HD 64
#define Hh 32
#define Ww 32
#define LQ 1025
#define LKV 257
#define TPAD 288
#define EPSf 1e-5f
#define SCALEf 0.05103103630798288f   // 384^-0.5

typedef float f32x4 __attribute__((ext_vector_type(4)));
typedef unsigned short u16x8 __attribute__((ext_vector_type(8)));
typedef unsigned short u16x4 __attribute__((ext_vector_type(4)));

__device__ __forceinline__ void mfma_16x16x32_bf16(f32x4& d, u16x8 a, u16x8 b) {
  // D = A*B + D ; A: 16x32, row = lane&15, k = (lane>>4)*8 + i (contig 8)
  //              B: 32x16, col = lane&15, k = (lane>>4)*8 + i
  //              D: col = lane&15, row = (lane>>4)*4 + reg
  asm("v_mfma_f32_16x16x32_bf16 %0, %1, %2, %0" : "+v"(d) : "v"(a), "v"(b));
}

__device__ __forceinline__ unsigned short f2bf(float f) {
  unsigned int u = __builtin_bit_cast(unsigned int, f);
  u += 0x7fffu + ((u >> 16) & 1u);
  return (unsigned short)(u >> 16);
}

__device__ __forceinline__ u16x4 f4tobf(f32x4 v, f32x4 inv, f32x4 add) {
  u16x4 r;
#pragma unroll
  for (int i = 0; i < 4; ++i) r[i] = f2bf(v[i] * inv[i] + add[i]);
  return r;
}

// ---------------- zero fill for v_t pad columns t in [256,288) ----------------
__global__ void zero_pad_kernel(unsigned short* v_t) {
  int i = blockIdx.x * 256 + threadIdx.x;            // Bn*Cc*32
  int t = 256 + (i & 31);
  int row = i >> 5;                                   // b*384 + o
  v_t[(size_t)row * TPAD + t] = 0;
}

// ---------------- fp32 -> bf16 weight conversion (GEMM weights) ---------------
__global__ void cvt_w_kernel(const float* wq, const float* wk, const float* wv,
                             unsigned short* dst) {
  int i = blockIdx.x * 256 + threadIdx.x;            // 3*384*384
  int which = i / (Cc * Cc), r = i % (Cc * Cc);
  const float* s = (which == 0) ? wq : (which == 1) ? wk : wv;
  dst[i] = f2bf(s[r]);
}

// ---------------- conv-weight transpose + BN fold -----------------------------
// wT[conv][tap][384] f32 ; bn[conv][2][384] f32 (inv, add)
__global__ void wprep_kernel(const float* cwq, const float* cwk, const float* cwv,
                             const float* gq, const float* bq, const float* mq, const float* vq,
                             const float* gk, const float* bk, const float* mk, const float* vk,
                             const float* gv, const float* bv, const float* mv, const float* vv,
                             float* wT, float* bn) {
  int i = blockIdx.x * 256 + threadIdx.x;
  if (i < 3 * 9 * Cc) {
    int which = i / (9 * Cc), r = i % (9 * Cc), t = r / Cc, c = r % Cc;
    const float* s = (which == 0) ? cwq : (which == 1) ? cwk : cwv;
    wT[(which * 9 + t) * Cc + c] = s[c * 9 + t];
  }
  if (i < 3 * Cc) {
    int which = i / Cc, c = i % Cc;
    const float* g = (which == 0) ? gq : (which == 1) ? gk : gv;
    const float* be = (which == 0) ? bq : (which == 1) ? bk : bv;
    const float* mu = (which == 0) ? mq : (which == 1) ? mk : mv;
    const float* va = (which == 0) ? vq : (which == 1) ? vk : vv;
    float inv = g[c] * rsqrtf(va[c] + EPSf);
    bn[which * 768 + c] = inv;
    bn[which * 768 + 384 + c] = be[c] - mu[c] * inv;
  }
}

// ---------------- cls token copy into activation row 0 ------------------------
__global__ void cls_kernel(const float* hidden, unsigned short* q_act,
                           unsigned short* k_act, unsigned short* v_act) {
  int i = blockIdx.x * 256 + threadIdx.x;            // Bn*Cc
  int b = i / Cc, c = i % Cc;
  unsigned short v = f2bf(hidden[(size_t)b * LQ * Cc + c]);
  q_act[(size_t)b * LQ * Cc + c] = v;
  k_act[(size_t)b * LKV * Cc + c] = v;
  v_act[(size_t)b * LKV * Cc + c] = v;
}

// ---------------- depthwise conv 3x3 s1 + BN for q, float4 over channels ------
// thread = (b, 4-row band, col j, 4 channels). 18 float4 loads / 4 outputs.
__global__ __launch_bounds__(256) void conv_q4_kernel(
    const float* hidden, const float* wT, const float* bn, unsigned short* q_act) {
  int e = blockIdx.x * 256 + threadIdx.x;
  int cg = e % 96; int r = e / 96;
  int j = r % Ww; r /= Ww;
  int band = r % 8; int b = r / 8;
  int c = cg * 4;
  int i0 = band * 4;

  f32x4 w[9];
#pragma unroll
  for (int t = 0; t < 9; ++t) w[t] = *(const f32x4*)&wT[t * Cc + c];

  const f32x4 fz = {0.f, 0.f, 0.f, 0.f};
  f32x4 acc[4] = {fz, fz, fz, fz};
  const float* hb = hidden + (size_t)b * LQ * Cc + Cc + c;
#pragma unroll
  for (int dh = 0; dh < 6; ++dh) {
    int h = i0 - 1 + dh;
    if (h < 0 || h >= Hh) continue;                  // block-uniform
    const float* hr = hb + (size_t)(h * Ww + j) * Cc;
    f32x4 xl = *(const f32x4*)(hr - Cc);             // in-bounds even at j==0
    f32x4 xc = *(const f32x4*)hr;
    f32x4 xr = (j < Ww - 1) ? *(const f32x4*)(hr + Cc) : fz;
    if (j == 0) xl = fz;
#pragma unroll
    for (int dy = 0; dy < 3; ++dy) {
      int oi = dh - dy;                              // compile-time
      if (oi >= 0 && oi < 4)
        acc[oi] += w[dy * 3 + 0] * xl + w[dy * 3 + 1] * xc + w[dy * 3 + 2] * xr;
    }
  }
  f32x4 inv = *(const f32x4*)&bn[c];
  f32x4 add = *(const f32x4*)&bn[384 + c];
#pragma unroll
  for (int oi = 0; oi < 4; ++oi) {
    int pos = (i0 + oi) * Ww + j;
    *(u16x4*)&q_act[((size_t)b * LQ + 1 + pos) * Cc + c] = f4tobf(acc[oi], inv, add);
  }
}

// ---------------- depthwise conv 3x3 s2 + BN for k,v, float4 over channels ----
__global__ __launch_bounds__(256) void conv_kv4_kernel(
    const float* hidden, const float* wT, const float* bn,
    unsigned short* k_act, unsigned short* v_act) {
  int e = blockIdx.x * 256 + threadIdx.x;
  int cg = e % 96; int r = e / 96;
  int j = r % 16; r /= 16;
  int i = r % 16; int b = r / 16;
  int c = cg * 4;

  f32x4 wk[9], wv[9];
#pragma unroll
  for (int t = 0; t < 9; ++t) {
    wk[t] = *(const f32x4*)&wT[(9 + t) * Cc + c];
    wv[t] = *(const f32x4*)&wT[(18 + t) * Cc + c];
  }
  const f32x4 fz = {0.f, 0.f, 0.f, 0.f};
  f32x4 acck = fz, accv = fz;
  const float* hb = hidden + (size_t)b * LQ * Cc + Cc + c;
#pragma unroll
  for (int dy = 0; dy < 3; ++dy) {
    int h = 2 * i + dy - 1;
    if (h < 0 || h >= Hh) continue;                  // block-uniform
#pragma unroll
    for (int dx = 0; dx < 3; ++dx) {
      int w2 = 2 * j + dx - 1;                       // only j==0,dx==0 underflows
      f32x4 x = *(const f32x4*)(hb + (size_t)(h * Ww + w2) * Cc);
      if (dx == 0 && j == 0) x = fz;
      acck += wk[dy * 3 + dx] * x;
      accv += wv[dy * 3 + dx] * x;
    }
  }
  f32x4 invk = *(const f32x4*)&bn[768 + c];
  f32x4 addk = *(const f32x4*)&bn[768 + 384 + c];
  f32x4 invv = *(const f32x4*)&bn[1536 + c];
  f32x4 addv = *(const f32x4*)&bn[1536 + 384 + c];
  int pos = i * 16 + j;
  *(u16x4*)&k_act[((size_t)b * LKV + 1 + pos) * Cc + c] = f4tobf(acck, invk, addk);
  *(u16x4*)&v_act[((size_t)b * LKV + 1 + pos) * Cc + c] = f4tobf(accv, invv, addv);
}

// ---------------- projection GEMM: out[m,o] = sum_c A[m,c]*W[o,c] + bias[o] ----
// mode 0 (q): out[m*384 + o]                     (m = b*1025 + l)
// mode 1 (k): b=m/257, t=m%257 -> out[(b*288+t)*384 + o]
// mode 2 (v): b=m/257, t=m%257 -> out[(b*384+o)*288 + t]   (transposed for PV)
__global__ __launch_bounds__(256) void proj_gemm_kernel(
    const unsigned short* A, const unsigned short* Wb, const float* bias,
    unsigned short* out, int mode) {
  __shared__ __align__(16) unsigned short a_lds[64][40];
  __shared__ __align__(16) unsigned short b_lds[128][40];
  int m0 = blockIdx.x * 64;
  int n0 = blockIdx.y * 128;
  int tid = threadIdx.x;
  int lane = tid & 63, wid = tid >> 6;
  int wm = wid >> 1, wn = wid & 1;
  int lr = lane & 15, lg = lane >> 4;

  const f32x4 fz = {0.f, 0.f, 0.f, 0.f};
  f32x4 acc[2][4];
#pragma unroll
  for (int i = 0; i < 2; ++i)
#pragma unroll
    for (int j = 0; j < 4; ++j) acc[i][j] = fz;

  int srow = tid >> 2, scg = tid & 3;
  for (int kk = 0; kk < Cc; kk += 32) {
    *(u16x8*)&a_lds[srow][scg * 8] =
        *(const u16x8*)&A[(size_t)(m0 + srow) * Cc + kk + scg * 8];
#pragma unroll
    for (int p = 0; p < 2; ++p) {
      int brow = srow + p * 64;
      *(u16x8*)&b_lds[brow][scg * 8] =
          *(const u16x8*)&Wb[(size_t)(n0 + brow) * Cc + kk + scg * 8];
    }
    __syncthreads();
    u16x8 af[2], bfr[4];
#pragma unroll
    for (int mi = 0; mi < 2; ++mi)
      af[mi] = *(const u16x8*)&a_lds[wm * 32 + mi * 16 + lr][lg * 8];
#pragma unroll
    for (int ni = 0; ni < 4; ++ni)
      bfr[ni] = *(const u16x8*)&b_lds[wn * 64 + ni * 16 + lr][lg * 8];
#pragma unroll
    for (int mi = 0; mi < 2; ++mi)
#pragma unroll
      for (int ni = 0; ni < 4; ++ni)
        mfma_16x16x32_bf16(acc[mi][ni], af[mi], bfr[ni]);
    __syncthreads();
  }

#pragma unroll
  for (int ni = 0; ni < 4; ++ni) {
    int col = n0 + wn * 64 + ni * 16 + lr;
    float bv = bias[col];
#pragma unroll
    for (int mi = 0; mi < 2; ++mi) {
      int rowbase = m0 + wm * 32 + mi * 16 + lg * 4;
#pragma unroll
      for (int rg = 0; rg < 4; ++rg) {
        int row = rowbase + rg;
        unsigned short bv16 = f2bf(acc[mi][ni][rg] + bv);
        if (mode == 0) {
          out[(size_t)row * Cc + col] = bv16;
        } else {
          int bb = row / LKV, t = row % LKV;
          if (mode == 1) out[((size_t)bb * TPAD + t) * Cc + col] = bv16;
          else           out[((size_t)bb * Cc + col) * TPAD + t] = bv16;
        }
      }
    }
  }
}

// ---------------- fused attention: LDS-staged K/V, swapped QK^T ----------------
// grid (4, NH, B); block = 4 waves. Each block: one (b,h), ~16 q-tiles.
// K_s: [288][64] bf16, XOR-swizzled (byte ^= (row&7)<<4)  -> conflict-balanced
// V_s: [64][296] bf16 (d-major, t padded to 296)          -> conflict-balanced
// P_s: per-wave [16][40] bf16 chunk buffer for P relayout
__global__ __launch_bounds__(256) void attn_kernel(
    const unsigned short* q_proj, const unsigned short* k_proj,
    const unsigned short* v_t, float* out) {
  __shared__ __align__(16) unsigned short K_s[288 * 64];
  __shared__ __align__(16) unsigned short V_s[64][296];
  __shared__ __align__(16) unsigned short P_s[4][16][40];
  int tid = threadIdx.x;
  int wid = tid >> 6, lane = tid & 63;
  int lr = lane & 15, lg = lane >> 4;
  int h = blockIdx.y, b = blockIdx.z, bx = blockIdx.x;

  // ---- cooperative staging: K (2304 chunks) + V (2304 chunks), 16B each ----
  const unsigned short* kg = k_proj + (size_t)b * TPAD * Cc + h * HD;
  const unsigned short* vg = v_t + ((size_t)b * Cc + h * HD) * TPAD;
#pragma unroll
  for (int i = 0; i < 9; ++i) {
    int c = tid + i * 256;
    int row = c >> 3, c16 = c & 7;                    // 8 chunks per 64-col K row
    u16x8 kv = *(const u16x8*)&kg[(size_t)row * Cc + c16 * 8];
    *(u16x8*)((char*)K_s + row * 128 + ((c16 * 16) ^ ((row & 7) << 4))) = kv;
    int rv = c / 36, cv = c - rv * 36;                // 36 chunks per 288-col V row
    u16x8 vv = *(const u16x8*)&vg[(size_t)rv * TPAD + cv * 8];
    *(u16x8*)((char*)&V_s[rv][0] + cv * 16) = vv;
  }
  __syncthreads();

  int start = (bx == 0) ? 0 : 1 + bx * 16;            // 65 = 17+16+16+16
  int end = 17 + bx * 16;
  const f32x4 fz = {0.f, 0.f, 0.f, 0.f};

  for (int qt = start + wid; qt < end; qt += 4) {
    int qbase = qt * 16;
    int qrow = qbase + lr; if (qrow > LQ - 1) qrow = LQ - 1;   // clamp tail
    const u16x8* qp =
        (const u16x8*)&q_proj[((size_t)b * LQ + qrow) * Cc + h * HD + lg * 8];
    u16x8 q0 = qp[0], q1 = qp[4];

    // ---- QK^T swapped: A = K-tile (row=t), B = Q (col=q) ----
    // lane (lr,lg) holds s[q=lr][t = 16T + lg*4 + rg]
    int kb0 = lr * 128 + ((lg * 16) ^ ((lr & 7) << 4));
    int kb1 = kb0 ^ 64;
    f32x4 s[18];
#pragma unroll
    for (int T = 0; T < 18; ++T) {
      u16x8 ka = *(const u16x8*)((const char*)K_s + kb0 + T * 2048);
      u16x8 kc = *(const u16x8*)((const char*)K_s + kb1 + T * 2048);
      s[T] = fz;
      mfma_16x16x32_bf16(s[T], ka, q0);
      mfma_16x16x32_bf16(s[T], kc, q1);
    }

    // ---- softmax over t for this lane's q-row ----
    float m = -1e30f;
#pragma unroll
    for (int T = 0; T < 18; ++T)
#pragma unroll
      for (int rg = 0; rg < 4; ++rg) {
        int t = T * 16 + lg * 4 + rg;
        float v = (t < LKV) ? s[T][rg] * SCALEf : -1e30f;
        s[T][rg] = v;
        m = fmaxf(m, v);
      }
    m = fmaxf(m, __shfl_xor(m, 16, 64));
    m = fmaxf(m, __shfl_xor(m, 32, 64));
    float sum = 0.f;
#pragma unroll
    for (int T = 0; T < 18; ++T)
#pragma unroll
      for (int rg = 0; rg < 4; ++rg) {
        float p = __expf(s[T][rg] - m);               // masked -> exp(-huge) = 0
        s[T][rg] = p;
        sum += p;
      }
    sum += __shfl_xor(sum, 16, 64);
    sum += __shfl_xor(sum, 32, 64);

    // ---- PV, chunked through per-wave P_s: t in [kk*32, kk*32+32) ----
    f32x4 o[4];
#pragma unroll
    for (int dt = 0; dt < 4; ++dt) o[dt] = fz;
#pragma unroll
    for (int kk = 0; kk < 9; ++kk) {
      u16x4 w0, w1;
#pragma unroll
      for (int rg = 0; rg < 4; ++rg) {
        w0[rg] = f2bf(s[2 * kk][rg]);
        w1[rg] = f2bf(s[2 * kk + 1][rg]);
      }
      *(u16x4*)&P_s[wid][lr][lg * 4] = w0;            // t_local = lg*4+rg
      *(u16x4*)&P_s[wid][lr][16 + lg * 4] = w1;       // t_local = 16+lg*4+rg
      asm volatile("s_waitcnt lgkmcnt(0)" ::: "memory");
      u16x8 pa = *(const u16x8*)&P_s[wid][lr][lg * 8];  // A: row=q=lr, k=t_local
#pragma unroll
      for (int dt = 0; dt < 4; ++dt) {
        u16x8 vb = *(const u16x8*)&V_s[dt * 16 + lr][kk * 32 + lg * 8];
        mfma_16x16x32_bf16(o[dt], pa, vb);
      }
    }

    // ---- epilogue: o D-layout col=d=lr, row=q=lg*4+rg; fetch 1/sum per row ----
    float rs = 1.0f / sum;
#pragma unroll
    for (int rg = 0; rg < 4; ++rg) {
      int row = qbase + lg * 4 + rg;
      float rsv = __shfl(rs, lg * 4 + rg, 64);
      if (row <= LQ - 1) {
#pragma unroll
        for (int dt = 0; dt < 4; ++dt)
          out[((size_t)b * LQ + row) * Cc + h * HD + dt * 16 + lr] = o[dt][rg] * rsv;
      }
    }
  }
}

extern "C" void kernel_launch(void* const* d_in, const int* in_sizes, int n_in,
                              void* d_out, int out_size, void* d_ws, size_t ws_size,
                              hipStream_t stream) {
  const float* hidden   = (const float*)d_in[0];
  const float* conv_q_w = (const float*)d_in[1];
  const float* bn_q_g   = (const float*)d_in[2];
  const float* bn_q_b   = (const float*)d_in[3];
  const float* bn_q_m   = (const float*)d_in[4];
  const float* bn_q_v   = (const float*)d_in[5];
  const float* w_q      = (const float*)d_in[6];
  const float* b_q      = (const float*)d_in[7];
  const float* conv_k_w = (const float*)d_in[8];
  const float* bn_k_g   = (const float*)d_in[9];
  const float* bn_k_b   = (const float*)d_in[10];
  const float* bn_k_m   = (const float*)d_in[11];
  const float* bn_k_v   = (const float*)d_in[12];
  const float* w_k      = (const float*)d_in[13];
  const float* b_k      = (const float*)d_in[14];
  const float* conv_v_w = (const float*)d_in[15];
  const float* bn_v_g   = (const float*)d_in[16];
  const float* bn_v_b   = (const float*)d_in[17];
  const float* bn_v_m   = (const float*)d_in[18];
  const float* bn_v_v   = (const float*)d_in[19];
  const float* w_v      = (const float*)d_in[20];
  const float* b_v      = (const float*)d_in[21];
  float* out = (float*)d_out;

  char* ws = (char*)d_ws;
  unsigned short* q_act  = (unsigned short*)(ws + 0);          // 65600*384
  unsigned short* k_act  = (unsigned short*)(ws + 50380800);   // 16448*384
  unsigned short* v_act  = (unsigned short*)(ws + 63012864);   // 16448*384
  unsigned short* q_proj = (unsigned short*)(ws + 75644928);   // 65600*384
  unsigned short* k_proj = (unsigned short*)(ws + 126025728);  // 64*288*384
  unsigned short* v_t    = (unsigned short*)(ws + 140181504);  // 64*384*288
  unsigned short* wbf    = (unsigned short*)(ws + 154337280);  // 3*384*384
  float*          wT     = (float*)(ws + 155222016);           // 3*9*384 f32
  float*          bnp    = (float*)(ws + 155263488);           // 3*2*384 f32

  zero_pad_kernel<<<(Bn * Cc * 32) / 256, 256, 0, stream>>>(v_t);
  cvt_w_kernel<<<(3 * Cc * Cc) / 256, 256, 0, stream>>>(w_q, w_k, w_v, wbf);
  wprep_kernel<<<41, 256, 0, stream>>>(conv_q_w, conv_k_w, conv_v_w,
      bn_q_g, bn_q_b, bn_q_m, bn_q_v,
      bn_k_g, bn_k_b, bn_k_m, bn_k_v,
      bn_v_g, bn_v_b, bn_v_m, bn_v_v, wT, bnp);
  cls_kernel<<<(Bn * Cc) / 256, 256, 0, stream>>>(hidden, q_act, k_act, v_act);
  conv_q4_kernel<<<(Bn * 8 * Ww * 96) / 256, 256, 0, stream>>>(hidden, wT, bnp, q_act);
  conv_kv4_kernel<<<(Bn * 16 * 16 * 96) / 256, 256, 0, stream>>>(
      hidden, wT, bnp, k_act, v_act);

  dim3 gq(1025, 3);
  proj_gemm_kernel<<<gq, 256, 0, stream>>>(q_act, wbf, b_q, q_proj, 0);
  dim3 gkv(257, 3);
  proj_gemm_kernel<<<gkv, 256, 0, stream>>>(k_act, wbf + Cc * Cc, b_k, k_proj, 1);
  proj_gemm_kernel<<<gkv, 256, 0, stream>>>(v_act, wbf + 2 * Cc * Cc, b_v, v_t, 2);

  dim3 ga(4, NHh, Bn);
  attn_kernel<<<ga, 256, 0, stream>>>(q_proj, k_proj, v_t, out);
}